// Round 1
// baseline (506.160 us; speedup 1.0000x reference)
//
#include <hip/hip_runtime.h>

#define NN 50000
#define NE 800000
#define ET (NE + NN)
#define SLOPE 0.2f
#define GEPS 1e-16f

// ---------------- CSR build ----------------
__global__ __launch_bounds__(256) void hist_kernel(const int* __restrict__ dst,
                                                   int* __restrict__ deg) {
  int i = blockIdx.x * 256 + threadIdx.x;
  if (i >= ET) return;
  int d = (i < NE) ? dst[i] : (i - NE);
  atomicAdd(&deg[d], 1);
}

__global__ __launch_bounds__(1024) void scan_kernel(const int* __restrict__ deg,
                                                    int* __restrict__ rowptr,
                                                    int* __restrict__ cursor) {
  __shared__ int lds[1024];
  int t = threadIdx.x;
  const int chunk = (NN + 1023) / 1024;  // 49
  int start = min(t * chunk, NN);
  int end = min(start + chunk, NN);
  int s = 0;
  for (int i = start; i < end; ++i) s += deg[i];
  lds[t] = s;
  __syncthreads();
  for (int off = 1; off < 1024; off <<= 1) {
    int v = (t >= off) ? lds[t - off] : 0;
    __syncthreads();
    lds[t] += v;
    __syncthreads();
  }
  int run = (t == 0) ? 0 : lds[t - 1];
  for (int i = start; i < end; ++i) {
    rowptr[i] = run;
    cursor[i] = run;
    run += deg[i];
  }
  if (start < NN && end == NN) rowptr[NN] = run;
}

__global__ __launch_bounds__(256) void scatter_kernel(const int* __restrict__ srcA,
                                                      const int* __restrict__ dstA,
                                                      int* __restrict__ cursor,
                                                      int* __restrict__ csr_src) {
  int i = blockIdx.x * 256 + threadIdx.x;
  if (i >= ET) return;
  int s, d;
  if (i < NE) { s = srcA[i]; d = dstA[i]; } else { s = d = i - NE; }
  int pos = atomicAdd(&cursor[d], 1);
  csr_src[pos] = s;
}

// ---------------- GEMM: H = A(NxK=128) @ B(128xNC), f32 ----------------
template <int NC>
__global__ __launch_bounds__(256) void gemm_kernel(const float* __restrict__ A,
                                                   const float* __restrict__ B,
                                                   float* __restrict__ H, int N) {
  constexpr int K = 128, KP = K + 1, BM = 64;
  constexpr int TX = NC / 4;       // threads along cols (each does 4 cols)
  constexpr int TY = 256 / TX;     // threads along rows
  constexpr int RPT = BM / TY;     // rows per thread
  __shared__ float Al[BM * KP];
  __shared__ float Bl[K * NC];
  const int tid = threadIdx.x;
  const int row0 = blockIdx.x * BM;
  for (int idx = tid; idx < BM * K / 4; idx += 256) {
    int r = (idx * 4) / K, k = (idx * 4) % K;
    int gr = row0 + r;
    float4 v = make_float4(0.f, 0.f, 0.f, 0.f);
    if (gr < N) v = *(const float4*)(A + (size_t)gr * K + k);
    float* p = Al + r * KP + k;
    p[0] = v.x; p[1] = v.y; p[2] = v.z; p[3] = v.w;
  }
  for (int idx = tid; idx < K * NC / 4; idx += 256)
    *(float4*)(Bl + idx * 4) = *(const float4*)(B + idx * 4);
  __syncthreads();
  const int tx = tid % TX, ty = tid / TX;
  float acc[RPT][4];
#pragma unroll
  for (int i = 0; i < RPT; ++i) {
    acc[i][0] = acc[i][1] = acc[i][2] = acc[i][3] = 0.f;
  }
#pragma unroll 4
  for (int k = 0; k < K; ++k) {
    float4 b = *(const float4*)(Bl + k * NC + tx * 4);
#pragma unroll
    for (int i = 0; i < RPT; ++i) {
      float a = Al[(ty * RPT + i) * KP + k];
      acc[i][0] += a * b.x;
      acc[i][1] += a * b.y;
      acc[i][2] += a * b.z;
      acc[i][3] += a * b.w;
    }
  }
#pragma unroll
  for (int i = 0; i < RPT; ++i) {
    int gr = row0 + ty * RPT + i;
    if (gr < N)
      *(float4*)(H + (size_t)gr * NC + tx * 4) =
          make_float4(acc[i][0], acc[i][1], acc[i][2], acc[i][3]);
  }
}

// ---------------- attention dot products: a_s[n,h], a_d[n,h] ----------------
template <int F, int C>
__global__ __launch_bounds__(256) void att_kernel(const float* __restrict__ Hm,
                                                  const float* __restrict__ att_s,
                                                  const float* __restrict__ att_d,
                                                  float* __restrict__ a_s,
                                                  float* __restrict__ a_d, int N) {
  constexpr int NH = F / C;
  constexpr int PB = 256 / F;
  int n = blockIdx.x * PB + threadIdx.x / F;
  int l = threadIdx.x % F;
  if (n >= N) return;
  float h = Hm[(size_t)n * F + l];
  float vs = h * att_s[l];
  float vd = h * att_d[l];
#pragma unroll
  for (int m = 1; m < C; m <<= 1) {
    vs += __shfl_xor(vs, m);
    vd += __shfl_xor(vd, m);
  }
  if ((l % C) == 0) {
    int hh = l / C;
    a_s[n * NH + hh] = vs;
    a_d[n * NH + hh] = vd;
  }
}

// ---------------- layer-1 aggregation: one wave per node, H=4, C=32 ----------------
__global__ __launch_bounds__(256) void gat1_kernel(const int* __restrict__ rowptr,
                                                   const int* __restrict__ csr_src,
                                                   const float* __restrict__ h1,
                                                   const float* __restrict__ as1,
                                                   const float* __restrict__ ad1,
                                                   const float* __restrict__ b1,
                                                   float* __restrict__ out1, int N) {
  int n = (blockIdx.x * 256 + threadIdx.x) >> 6;
  int l = threadIdx.x & 63;
  if (n >= N) return;
  int start = rowptr[n], end = rowptr[n + 1];
  int hB = l >> 4;  // head of channels 2l, 2l+1
  float ad_b = ad1[n * 4 + hB];
  float ad_a = ad1[n * 4 + (l & 3)];
  // pass A: segment max (16 edges x 4 heads per iteration)
  float mv = -1e30f;
  for (int base = start; base < end; base += 16) {
    int eidx = base + (l >> 2);
    if (eidx < end) {
      int s = csr_src[eidx];
      float a = as1[s * 4 + (l & 3)] + ad_a;
      a = (a > 0.f) ? a : SLOPE * a;
      mv = fmaxf(mv, a);
    }
  }
  mv = fmaxf(mv, __shfl_xor(mv, 4));
  mv = fmaxf(mv, __shfl_xor(mv, 8));
  mv = fmaxf(mv, __shfl_xor(mv, 16));
  mv = fmaxf(mv, __shfl_xor(mv, 32));
  float m_h = __shfl(mv, hB);  // lane h (h<4) holds max of head h
  // pass B: unnormalized weighted accumulation; lane owns channels 2l, 2l+1
  float accx = 0.f, accy = 0.f, z = 0.f;
  for (int e = start; e < end; ++e) {
    int s = csr_src[e];
    float a = as1[s * 4 + hB] + ad_b;
    a = (a > 0.f) ? a : SLOPE * a;
    float w = __expf(a - m_h);
    float2 hv = *(const float2*)(h1 + (size_t)s * 128 + 2 * l);
    accx += w * hv.x;
    accy += w * hv.y;
    z += w;
  }
  float inv = 1.f / (z + GEPS);
  float ox = fmaxf(accx * inv + b1[2 * l], 0.f);
  float oy = fmaxf(accy * inv + b1[2 * l + 1], 0.f);
  *(float2*)(out1 + (size_t)n * 128 + 2 * l) = make_float2(ox, oy);
}

// ---------------- layer-2 aggregation: one wave per node, H=1, C=64 ----------------
__global__ __launch_bounds__(256) void gat2_kernel(const int* __restrict__ rowptr,
                                                   const int* __restrict__ csr_src,
                                                   const float* __restrict__ h2,
                                                   const float* __restrict__ as2,
                                                   const float* __restrict__ ad2,
                                                   const float* __restrict__ b2,
                                                   float* __restrict__ out, int N) {
  int n = (blockIdx.x * 256 + threadIdx.x) >> 6;
  int l = threadIdx.x & 63;
  if (n >= N) return;
  int start = rowptr[n], end = rowptr[n + 1];
  float ad = ad2[n];
  float mv = -1e30f;
  for (int base = start; base < end; base += 64) {
    int eidx = base + l;
    if (eidx < end) {
      int s = csr_src[eidx];
      float a = as2[s] + ad;
      a = (a > 0.f) ? a : SLOPE * a;
      mv = fmaxf(mv, a);
    }
  }
#pragma unroll
  for (int m = 1; m <= 32; m <<= 1) mv = fmaxf(mv, __shfl_xor(mv, m));
  float acc = 0.f, z = 0.f;
  for (int e = start; e < end; ++e) {
    int s = csr_src[e];
    float a = as2[s] + ad;
    a = (a > 0.f) ? a : SLOPE * a;
    float w = __expf(a - mv);
    acc += w * h2[(size_t)s * 64 + l];
    z += w;
  }
  out[(size_t)n * 64 + l] = fmaxf(acc / (z + GEPS) + b2[l], 0.f);
}

extern "C" void kernel_launch(void* const* d_in, const int* in_sizes, int n_in,
                              void* d_out, int out_size, void* d_ws, size_t ws_size,
                              hipStream_t stream) {
  const float* x = (const float*)d_in[0];
  const int* ei = (const int*)d_in[1];
  const float* W1 = (const float*)d_in[2];
  const float* att_s1 = (const float*)d_in[3];
  const float* att_d1 = (const float*)d_in[4];
  const float* b1 = (const float*)d_in[5];
  const float* W2 = (const float*)d_in[6];
  const float* att_s2 = (const float*)d_in[7];
  const float* att_d2 = (const float*)d_in[8];
  const float* b2 = (const float*)d_in[9];
  float* out = (float*)d_out;

  char* ws = (char*)d_ws;
  size_t off = 0;
  auto alloc = [&](size_t bytes) {
    off = (off + 255) & ~(size_t)255;
    void* p = ws + off;
    off += bytes;
    return p;
  };
  int* deg = (int*)alloc((NN + 1) * sizeof(int));
  int* rowptr = (int*)alloc((NN + 1) * sizeof(int));
  int* cursor = (int*)alloc((size_t)NN * sizeof(int));
  int* csr_src = (int*)alloc((size_t)ET * sizeof(int));
  float* h1 = (float*)alloc((size_t)NN * 128 * sizeof(float));
  float* as1 = (float*)alloc((size_t)NN * 4 * sizeof(float));
  float* ad1 = (float*)alloc((size_t)NN * 4 * sizeof(float));
  float* out1 = (float*)alloc((size_t)NN * 128 * sizeof(float));
  float* hh2 = h1;   // layer-2 features reuse h1 space (h1 dead after gat1)
  float* as2 = as1;  // reuse
  float* ad2 = ad1;  // reuse

  const int* src = ei;
  const int* dst = ei + NE;

  hipMemsetAsync(deg, 0, (NN + 1) * sizeof(int), stream);
  int ebks = (ET + 255) / 256;
  hipLaunchKernelGGL(hist_kernel, dim3(ebks), dim3(256), 0, stream, dst, deg);
  hipLaunchKernelGGL(scan_kernel, dim3(1), dim3(1024), 0, stream, deg, rowptr, cursor);
  hipLaunchKernelGGL(scatter_kernel, dim3(ebks), dim3(256), 0, stream, src, dst, cursor,
                     csr_src);

  hipLaunchKernelGGL((gemm_kernel<128>), dim3((NN + 63) / 64), dim3(256), 0, stream, x,
                     W1, h1, NN);
  hipLaunchKernelGGL((att_kernel<128, 32>), dim3((NN + 1) / 2), dim3(256), 0, stream,
                     h1, att_s1, att_d1, as1, ad1, NN);
  hipLaunchKernelGGL(gat1_kernel, dim3((NN + 3) / 4), dim3(256), 0, stream, rowptr,
                     csr_src, h1, as1, ad1, b1, out1, NN);

  hipLaunchKernelGGL((gemm_kernel<64>), dim3((NN + 63) / 64), dim3(256), 0, stream,
                     out1, W2, hh2, NN);
  hipLaunchKernelGGL((att_kernel<64, 64>), dim3((NN + 3) / 4), dim3(256), 0, stream,
                     hh2, att_s2, att_d2, as2, ad2, NN);
  hipLaunchKernelGGL(gat2_kernel, dim3((NN + 3) / 4), dim3(256), 0, stream, rowptr,
                     csr_src, hh2, as2, ad2, b2, out, NN);
}

// Round 2
// 306.782 us; speedup vs baseline: 1.6499x; 1.6499x over previous
//
#include <hip/hip_runtime.h>

#define NN 50000
#define NE 800000
#define ET (NE + NN)
#define SLOPE 0.2f
#define GEPS 1e-16f
#define NB 196  // (NN+255)/256

// ---------------- CSR build ----------------
__global__ __launch_bounds__(256) void hist_kernel(const int* __restrict__ dst,
                                                   int* __restrict__ deg) {
  int i = blockIdx.x * 256 + threadIdx.x;
  if (i >= ET) return;
  int d = (i < NE) ? dst[i] : (i - NE);
  atomicAdd(&deg[d], 1);
}

// partial sums: one block of 256 sums 256 degrees
__global__ __launch_bounds__(256) void part_kernel(const int* __restrict__ deg,
                                                   int* __restrict__ bsum) {
  __shared__ int lds[256];
  int t = threadIdx.x;
  int i = blockIdx.x * 256 + t;
  lds[t] = (i < NN) ? deg[i] : 0;
  __syncthreads();
  for (int off = 128; off > 0; off >>= 1) {
    if (t < off) lds[t] += lds[t + off];
    __syncthreads();
  }
  if (t == 0) bsum[blockIdx.x] = lds[0];
}

// exclusive scan of NB block sums (single small block)
__global__ __launch_bounds__(256) void bscan_kernel(const int* __restrict__ bsum,
                                                    int* __restrict__ boff) {
  __shared__ int lds[256];
  int t = threadIdx.x;
  int v = (t < NB) ? bsum[t] : 0;
  lds[t] = v;
  __syncthreads();
  for (int off = 1; off < 256; off <<= 1) {
    int u = (t >= off) ? lds[t - off] : 0;
    __syncthreads();
    lds[t] += u;
    __syncthreads();
  }
  if (t < NB) boff[t] = lds[t] - v;
}

// per-block scan + apply offset -> rowptr & cursor
__global__ __launch_bounds__(256) void rowptr_kernel(const int* __restrict__ deg,
                                                     const int* __restrict__ boff,
                                                     int* __restrict__ rowptr,
                                                     int* __restrict__ cursor) {
  __shared__ int lds[256];
  int t = threadIdx.x;
  int i = blockIdx.x * 256 + t;
  int v = (i < NN) ? deg[i] : 0;
  lds[t] = v;
  __syncthreads();
  for (int off = 1; off < 256; off <<= 1) {
    int u = (t >= off) ? lds[t - off] : 0;
    __syncthreads();
    lds[t] += u;
    __syncthreads();
  }
  if (i < NN) {
    int excl = boff[blockIdx.x] + lds[t] - v;
    rowptr[i] = excl;
    cursor[i] = excl;
    if (i == NN - 1) rowptr[NN] = excl + v;
  }
}

__global__ __launch_bounds__(256) void scatter_kernel(const int* __restrict__ srcA,
                                                      const int* __restrict__ dstA,
                                                      int* __restrict__ cursor,
                                                      int* __restrict__ csr_src) {
  int i = blockIdx.x * 256 + threadIdx.x;
  if (i >= ET) return;
  int s, d;
  if (i < NE) { s = srcA[i]; d = dstA[i]; } else { s = d = i - NE; }
  int pos = atomicAdd(&cursor[d], 1);
  csr_src[pos] = s;
}

// ---------------- GEMM: H = A(NxK=128) @ B(128xNC), f32 ----------------
template <int NC>
__global__ __launch_bounds__(256) void gemm_kernel(const float* __restrict__ A,
                                                   const float* __restrict__ B,
                                                   float* __restrict__ H, int N) {
  constexpr int K = 128, KP = K + 1, BM = 64;
  constexpr int TX = NC / 4;
  constexpr int TY = 256 / TX;
  constexpr int RPT = BM / TY;
  __shared__ float Al[BM * KP];
  __shared__ float Bl[K * NC];
  const int tid = threadIdx.x;
  const int row0 = blockIdx.x * BM;
  for (int idx = tid; idx < BM * K / 4; idx += 256) {
    int r = (idx * 4) / K, k = (idx * 4) % K;
    int gr = row0 + r;
    float4 v = make_float4(0.f, 0.f, 0.f, 0.f);
    if (gr < N) v = *(const float4*)(A + (size_t)gr * K + k);
    float* p = Al + r * KP + k;
    p[0] = v.x; p[1] = v.y; p[2] = v.z; p[3] = v.w;
  }
  for (int idx = tid; idx < K * NC / 4; idx += 256)
    *(float4*)(Bl + idx * 4) = *(const float4*)(B + idx * 4);
  __syncthreads();
  const int tx = tid % TX, ty = tid / TX;
  float acc[RPT][4];
#pragma unroll
  for (int i = 0; i < RPT; ++i) {
    acc[i][0] = acc[i][1] = acc[i][2] = acc[i][3] = 0.f;
  }
#pragma unroll 4
  for (int k = 0; k < K; ++k) {
    float4 b = *(const float4*)(Bl + k * NC + tx * 4);
#pragma unroll
    for (int i = 0; i < RPT; ++i) {
      float a = Al[(ty * RPT + i) * KP + k];
      acc[i][0] += a * b.x;
      acc[i][1] += a * b.y;
      acc[i][2] += a * b.z;
      acc[i][3] += a * b.w;
    }
  }
#pragma unroll
  for (int i = 0; i < RPT; ++i) {
    int gr = row0 + ty * RPT + i;
    if (gr < N)
      *(float4*)(H + (size_t)gr * NC + tx * 4) =
          make_float4(acc[i][0], acc[i][1], acc[i][2], acc[i][3]);
  }
}

// ---------------- attention dot products ----------------
template <int F, int C>
__global__ __launch_bounds__(256) void att_kernel(const float* __restrict__ Hm,
                                                  const float* __restrict__ att_s,
                                                  const float* __restrict__ att_d,
                                                  float* __restrict__ a_s,
                                                  float* __restrict__ a_d, int N) {
  constexpr int NH = F / C;
  constexpr int PB = 256 / F;
  int n = blockIdx.x * PB + threadIdx.x / F;
  int l = threadIdx.x % F;
  if (n >= N) return;
  float h = Hm[(size_t)n * F + l];
  float vs = h * att_s[l];
  float vd = h * att_d[l];
#pragma unroll
  for (int m = 1; m < C; m <<= 1) {
    vs += __shfl_xor(vs, m);
    vd += __shfl_xor(vd, m);
  }
  if ((l % C) == 0) {
    int hh = l / C;
    a_s[n * NH + hh] = vs;
    a_d[n * NH + hh] = vd;
  }
}

// ---------------- layer-1 aggregation: wave/node, 2 edges per iter ----------------
// lanes 0-31 handle even edges, 32-63 odd edges; each lane owns 4 channels.
__global__ __launch_bounds__(256) void gat1_kernel(const int* __restrict__ rowptr,
                                                   const int* __restrict__ csr_src,
                                                   const float* __restrict__ h1,
                                                   const float* __restrict__ as1,
                                                   const float* __restrict__ ad1,
                                                   const float* __restrict__ b1,
                                                   float* __restrict__ out1, int N) {
  int n = (blockIdx.x * 256 + threadIdx.x) >> 6;
  int l = threadIdx.x & 63;
  if (n >= N) return;
  int start = rowptr[n], end = rowptr[n + 1];
  int c = l & 31, half = l >> 5;
  int hB = c >> 3;  // head of channels 4c..4c+3
  float ad_b = ad1[n * 4 + hB];
  float ax = 0.f, ay = 0.f, az = 0.f, aw = 0.f, z = 0.f;
  for (int e = start + half; e < end; e += 2) {
    int s = csr_src[e];
    float a = as1[s * 4 + hB] + ad_b;
    a = (a > 0.f) ? a : SLOPE * a;
    float w = __expf(a);
    float4 g = *(const float4*)(h1 + (size_t)s * 128 + 4 * c);
    ax += w * g.x; ay += w * g.y; az += w * g.z; aw += w * g.w;
    z += w;
  }
  ax += __shfl_xor(ax, 32);
  ay += __shfl_xor(ay, 32);
  az += __shfl_xor(az, 32);
  aw += __shfl_xor(aw, 32);
  z += __shfl_xor(z, 32);
  if (half == 0) {
    float inv = 1.f / (z + GEPS);
    float4 bb = *(const float4*)(b1 + 4 * c);
    float4 o;
    o.x = fmaxf(ax * inv + bb.x, 0.f);
    o.y = fmaxf(ay * inv + bb.y, 0.f);
    o.z = fmaxf(az * inv + bb.z, 0.f);
    o.w = fmaxf(aw * inv + bb.w, 0.f);
    *(float4*)(out1 + (size_t)n * 128 + 4 * c) = o;
  }
}

// ---------------- layer-2 aggregation: wave/node, 4 edges per iter ----------------
// 16-lane quarters each handle one edge; lane owns 4 channels of 64.
__global__ __launch_bounds__(256) void gat2_kernel(const int* __restrict__ rowptr,
                                                   const int* __restrict__ csr_src,
                                                   const float* __restrict__ h2,
                                                   const float* __restrict__ as2,
                                                   const float* __restrict__ ad2,
                                                   const float* __restrict__ b2,
                                                   float* __restrict__ out, int N) {
  int n = (blockIdx.x * 256 + threadIdx.x) >> 6;
  int l = threadIdx.x & 63;
  if (n >= N) return;
  int start = rowptr[n], end = rowptr[n + 1];
  int c = l & 15, q = l >> 4;
  float ad = ad2[n];
  float ax = 0.f, ay = 0.f, az = 0.f, aw = 0.f, z = 0.f;
  for (int e = start + q; e < end; e += 4) {
    int s = csr_src[e];
    float a = as2[s] + ad;
    a = (a > 0.f) ? a : SLOPE * a;
    float w = __expf(a);
    float4 g = *(const float4*)(h2 + (size_t)s * 64 + 4 * c);
    ax += w * g.x; ay += w * g.y; az += w * g.z; aw += w * g.w;
    z += w;
  }
  ax += __shfl_xor(ax, 16); ax += __shfl_xor(ax, 32);
  ay += __shfl_xor(ay, 16); ay += __shfl_xor(ay, 32);
  az += __shfl_xor(az, 16); az += __shfl_xor(az, 32);
  aw += __shfl_xor(aw, 16); aw += __shfl_xor(aw, 32);
  z += __shfl_xor(z, 16);  z += __shfl_xor(z, 32);
  if (q == 0) {
    float inv = 1.f / (z + GEPS);
    float4 bb = *(const float4*)(b2 + 4 * c);
    float4 o;
    o.x = fmaxf(ax * inv + bb.x, 0.f);
    o.y = fmaxf(ay * inv + bb.y, 0.f);
    o.z = fmaxf(az * inv + bb.z, 0.f);
    o.w = fmaxf(aw * inv + bb.w, 0.f);
    *(float4*)(out + (size_t)n * 64 + 4 * c) = o;
  }
}

extern "C" void kernel_launch(void* const* d_in, const int* in_sizes, int n_in,
                              void* d_out, int out_size, void* d_ws, size_t ws_size,
                              hipStream_t stream) {
  const float* x = (const float*)d_in[0];
  const int* ei = (const int*)d_in[1];
  const float* W1 = (const float*)d_in[2];
  const float* att_s1 = (const float*)d_in[3];
  const float* att_d1 = (const float*)d_in[4];
  const float* b1 = (const float*)d_in[5];
  const float* W2 = (const float*)d_in[6];
  const float* att_s2 = (const float*)d_in[7];
  const float* att_d2 = (const float*)d_in[8];
  const float* b2 = (const float*)d_in[9];
  float* out = (float*)d_out;

  char* ws = (char*)d_ws;
  size_t off = 0;
  auto alloc = [&](size_t bytes) {
    off = (off + 255) & ~(size_t)255;
    void* p = ws + off;
    off += bytes;
    return p;
  };
  int* deg = (int*)alloc((NN + 1) * sizeof(int));
  int* rowptr = (int*)alloc((NN + 1) * sizeof(int));
  int* cursor = (int*)alloc((size_t)NN * sizeof(int));
  int* bsum = (int*)alloc(NB * sizeof(int));
  int* boff = (int*)alloc(NB * sizeof(int));
  int* csr_src = (int*)alloc((size_t)ET * sizeof(int));
  float* h1 = (float*)alloc((size_t)NN * 128 * sizeof(float));
  float* as1 = (float*)alloc((size_t)NN * 4 * sizeof(float));
  float* ad1 = (float*)alloc((size_t)NN * 4 * sizeof(float));
  float* out1 = (float*)alloc((size_t)NN * 128 * sizeof(float));
  float* hh2 = h1;   // layer-2 features reuse h1 (dead after gat1)
  float* as2 = as1;
  float* ad2 = ad1;

  const int* src = ei;
  const int* dst = ei + NE;

  hipMemsetAsync(deg, 0, (NN + 1) * sizeof(int), stream);
  int ebks = (ET + 255) / 256;
  hipLaunchKernelGGL(hist_kernel, dim3(ebks), dim3(256), 0, stream, dst, deg);
  hipLaunchKernelGGL(part_kernel, dim3(NB), dim3(256), 0, stream, deg, bsum);
  hipLaunchKernelGGL(bscan_kernel, dim3(1), dim3(256), 0, stream, bsum, boff);
  hipLaunchKernelGGL(rowptr_kernel, dim3(NB), dim3(256), 0, stream, deg, boff, rowptr,
                     cursor);
  hipLaunchKernelGGL(scatter_kernel, dim3(ebks), dim3(256), 0, stream, src, dst, cursor,
                     csr_src);

  hipLaunchKernelGGL((gemm_kernel<128>), dim3((NN + 63) / 64), dim3(256), 0, stream, x,
                     W1, h1, NN);
  hipLaunchKernelGGL((att_kernel<128, 32>), dim3((NN + 1) / 2), dim3(256), 0, stream,
                     h1, att_s1, att_d1, as1, ad1, NN);
  hipLaunchKernelGGL(gat1_kernel, dim3((NN + 3) / 4), dim3(256), 0, stream, rowptr,
                     csr_src, h1, as1, ad1, b1, out1, NN);

  hipLaunchKernelGGL((gemm_kernel<64>), dim3((NN + 63) / 64), dim3(256), 0, stream,
                     out1, W2, hh2, NN);
  hipLaunchKernelGGL((att_kernel<64, 64>), dim3((NN + 3) / 4), dim3(256), 0, stream,
                     hh2, att_s2, att_d2, as2, ad2, NN);
  hipLaunchKernelGGL(gat2_kernel, dim3((NN + 3) / 4), dim3(256), 0, stream, rowptr,
                     csr_src, hh2, as2, ad2, b2, out, NN);
}